// Round 1
// baseline (420.600 us; speedup 1.0000x reference)
//
#include <hip/hip_runtime.h>
#include <hip/hip_bf16.h>

#define DIM 4096
#define NUM_SHARDS 8
#define TOTAL_ELEMS (4 * 4096 * 4096)   // BATCH * SEQ * DIM
#define TOTAL_F4 (TOTAL_ELEMS / 4)      // 16,777,216 float4 elements
#define DIM_F4 (DIM / 4)                // 1024 float4 per row

// Kernel 1: collapse the shard gather into a flat per-dim weight vector.
// w[d] = shards[shard_map[d] * DIM + d]. 16 KiB output into d_ws.
__global__ void build_w_kernel(const float* __restrict__ shards,
                               const int* __restrict__ shard_map,
                               float* __restrict__ w) {
    int d = blockIdx.x * blockDim.x + threadIdx.x;
    if (d < DIM) {
        w[d] = shards[shard_map[d] * DIM + d];
    }
}

// Kernel 2: pure bandwidth elementwise multiply, float4-vectorized.
// i & 1023 maps a flat float4 index to its position within the DIM axis
// (DIM/4 = 1024, power of two). w table (16 KiB) stays L1/L2-resident.
__global__ __launch_bounds__(256) void scale_kernel(const float4* __restrict__ x,
                                                    const float4* __restrict__ w,
                                                    float4* __restrict__ out) {
    int i = blockIdx.x * 256 + threadIdx.x;
    float4 xv = x[i];
    float4 wv = w[i & (DIM_F4 - 1)];
    float4 ov;
    ov.x = xv.x * wv.x;
    ov.y = xv.y * wv.y;
    ov.z = xv.z * wv.z;
    ov.w = xv.w * wv.w;
    out[i] = ov;
}

extern "C" void kernel_launch(void* const* d_in, const int* in_sizes, int n_in,
                              void* d_out, int out_size, void* d_ws, size_t ws_size,
                              hipStream_t stream) {
    const float* x = (const float*)d_in[0];
    const float* shards = (const float*)d_in[1];
    const int* shard_map = (const int*)d_in[2];
    float* w = (float*)d_ws;   // 16 KiB scratch; rebuilt every call (ws is re-poisoned)
    float* out = (float*)d_out;

    build_w_kernel<<<DIM / 256, 256, 0, stream>>>(shards, shard_map, w);

    scale_kernel<<<TOTAL_F4 / 256, 256, 0, stream>>>(
        (const float4*)x, (const float4*)w, (float4*)out);
}